// Round 10
// baseline (149.464 us; speedup 1.0000x reference)
//
#include <hip/hip_runtime.h>

#define EPS 1e-5f

#define BATCH 16
#define LEN   1024
#define C0    8
#define C1    32
#define C2    64
#define NODES 128
#define NF1   100
#define NF2   128

// workspace layout (float offsets) — round-6 proven. cnt[0..16] zeroed by kB
// (visible to kC via dispatch boundary); zzp fully written before read.
#define OFF_C1   0          // 16*32*1024 = 524288
#define OFF_C2   524288     // 16*64*1024 = 1048576
#define OFF_S1P  1572864    // 256 blocks * 64
#define OFF_S2P  1589248    // 256 blocks * 128
#define OFF_ZZP  1622016    // 16 slices * 16 n * 100 f = 25600
#define OFF_CNT  1647616    // 17 uints: [0]=global, [1+n]=per-n

#define AL(p) __hip_atomic_load((p), __ATOMIC_RELAXED, __HIP_MEMORY_SCOPE_AGENT)

// ---------------- kA: conv1 (8->32, K=5, pad 2) + bias -> c1, BN1 block partials
__global__ __launch_bounds__(256)
void kA(const float* __restrict__ x, const float* __restrict__ w,
        const float* __restrict__ bias, float* __restrict__ c1,
        float* __restrict__ s1p) {
    int tid = threadIdx.x, b = blockIdx.x;
    int lane = tid & 63, wave = tid >> 6;
    int n = b >> 4, lt = b & 15;
    int l = lt * 64 + lane;
    int cg8 = __builtin_amdgcn_readfirstlane(wave * 8);

    float xr[5][8];
#pragma unroll
    for (int dl = 0; dl < 5; ++dl) {
        int lw = l + dl - 2;
        if (lw >= 0 && lw < LEN) {
            const float4* p = (const float4*)(x + ((size_t)n * LEN + lw) * C0);
            float4 a = p[0], b4 = p[1];
            xr[dl][0] = a.x;  xr[dl][1] = a.y;  xr[dl][2] = a.z;  xr[dl][3] = a.w;
            xr[dl][4] = b4.x; xr[dl][5] = b4.y; xr[dl][6] = b4.z; xr[dl][7] = b4.w;
        } else {
#pragma unroll
            for (int ci = 0; ci < 8; ++ci) xr[dl][ci] = 0.f;
        }
    }
#pragma unroll
    for (int u = 0; u < 8; ++u) {
        int c = cg8 + u;
        float acc = bias[c];
        const float* wc = w + c * 40;
#pragma unroll
        for (int ci = 0; ci < 8; ++ci)
#pragma unroll
            for (int dl = 0; dl < 5; ++dl)
                acc += xr[dl][ci] * wc[ci * 5 + dl];
        c1[((size_t)n * C1 + c) * LEN + l] = acc;

        float s = acc, q = acc * acc;
#pragma unroll
        for (int off = 32; off >= 1; off >>= 1) {
            s += __shfl_xor(s, off);
            q += __shfl_xor(q, off);
        }
        if (lane == 0) {
            s1p[b * 64 + c * 2]     = s;
            s1p[b * 64 + c * 2 + 1] = q;
        }
    }
}

// ---------------- kB: BN1 reduce; BN1+ReLU -> conv2 (32->64) -> c2, BN2 partials; zero cnt
__global__ __launch_bounds__(256)
void kB(const float* __restrict__ c1, const float* __restrict__ w,
        const float* __restrict__ bias,
        const float* __restrict__ g1, const float* __restrict__ bb1,
        const float* __restrict__ s1p,
        float* __restrict__ c2, float* __restrict__ s2p,
        unsigned* __restrict__ cnt) {
    int tid = threadIdx.x, b = blockIdx.x;
    int lane = tid & 63, wave = tid >> 6;

    if (b == 0 && tid < 17) cnt[tid] = 0u;

    __shared__ float sc1[32], sh1[32];
    __shared__ __align__(16) float a1[32 * 68];
    __shared__ float redw[256];

    {
        float a0=0,a1_=0,a2=0,a3=0,a4=0,a5=0,a6=0,a7=0;
        int b0 = wave * 64;
        for (int i = 0; i < 64; i += 8) {
            a0  += s1p[(size_t)(b0+i  ) * 64 + lane];
            a1_ += s1p[(size_t)(b0+i+1) * 64 + lane];
            a2  += s1p[(size_t)(b0+i+2) * 64 + lane];
            a3  += s1p[(size_t)(b0+i+3) * 64 + lane];
            a4  += s1p[(size_t)(b0+i+4) * 64 + lane];
            a5  += s1p[(size_t)(b0+i+5) * 64 + lane];
            a6  += s1p[(size_t)(b0+i+6) * 64 + lane];
            a7  += s1p[(size_t)(b0+i+7) * 64 + lane];
        }
        redw[wave * 64 + lane] = ((a0+a1_)+(a2+a3)) + ((a4+a5)+(a6+a7));
    }
    __syncthreads();
    if (tid < 64)
        redw[tid] = redw[tid] + redw[64 + tid] + redw[128 + tid] + redw[192 + tid];
    __syncthreads();
    if (tid < 32) {
        float s = redw[tid * 2], q = redw[tid * 2 + 1];
        float mean = s * (1.f / 16384.f);
        float var  = q * (1.f / 16384.f) - mean * mean;
        float rs   = rsqrtf(var + EPS);
        float sc   = g1[tid] * rs;
        sc1[tid] = sc;
        sh1[tid] = bb1[tid] - mean * sc;
    }
    __syncthreads();

    int n = b >> 4, lt = b & 15;
    int lbase = lt * 64;

    for (int idx = tid; idx < 32 * 68; idx += 256) {
        int ci = idx / 68, lo = idx - ci * 68;
        int lg = lbase + lo - 2;
        float v = 0.f;
        if (lg >= 0 && lg < LEN) v = c1[((size_t)n * C1 + ci) * LEN + lg];
        a1[idx] = fmaxf(0.f, v * sc1[ci] + sh1[ci]);
    }
    __syncthreads();

    int l = lane;
    int cobase = __builtin_amdgcn_readfirstlane(wave * 16);

    float acc[16];
#pragma unroll
    for (int u = 0; u < 16; ++u) acc[u] = bias[cobase + u];

    for (int ci = 0; ci < 32; ++ci) {
        float v0 = a1[ci * 68 + l + 0];
        float v1 = a1[ci * 68 + l + 1];
        float v2 = a1[ci * 68 + l + 2];
        float v3 = a1[ci * 68 + l + 3];
        float v4 = a1[ci * 68 + l + 4];
#pragma unroll
        for (int u = 0; u < 16; ++u) {
            const float* wp = w + ((size_t)(cobase + u) * 32 + ci) * 5;
            acc[u] += v0 * wp[0] + v1 * wp[1] + v2 * wp[2] + v3 * wp[3] + v4 * wp[4];
        }
    }

    int lg = lbase + l;
#pragma unroll
    for (int u = 0; u < 16; ++u)
        c2[((size_t)n * C2 + cobase + u) * LEN + lg] = acc[u];

    for (int u = 0; u < 16; ++u) {
        float s = acc[u], q = acc[u] * acc[u];
#pragma unroll
        for (int off = 32; off >= 1; off >>= 1) {
            s += __shfl_xor(s, off);
            q += __shfl_xor(q, off);
        }
        if (lane == 0) {
            int c = cobase + u;
            s2p[b * 128 + c * 2]     = s;
            s2p[b * 128 + c * 2 + 1] = q;
        }
    }
}

// ---------------- kC: 256 blocks x 1024 threads. BN2 reduce; pool (4j x 4k per
// lane, shfl-combined i-halves); FC1 slice -> zzp; 2-level ticket -> BN3+FC2
__global__ __launch_bounds__(1024)
void kC(const float* __restrict__ bmat, const float* __restrict__ c2,
        const float* __restrict__ g2, const float* __restrict__ bb2,
        const float* __restrict__ s2p, const float* __restrict__ w1,
        const float* __restrict__ b1f, const float* __restrict__ g3,
        const float* __restrict__ b3, const float* __restrict__ w2,
        const float* __restrict__ b2f,
        float* __restrict__ zzp, unsigned* __restrict__ cnt,
        float* __restrict__ out) {
    int tid = threadIdx.x, b = blockIdx.x;
    int lane = tid & 63, wave = tid >> 6;          // 16 waves
    int n = b >> 4, jt = (b >> 2) & 3, ks = b & 3;
    int jbase = jt * 32, kbase = ks * 16;

    __shared__ __align__(16) float smem[14368];
    __shared__ unsigned sflag;
    float* bt   = smem;            // 256 x 36 = 9216
    float* ht   = smem + 9216;     // 256 x 20 = 5120 -> 14336
    float* sc2s = smem + 14336;    // 16
    float* sh2s = smem + 14352;    // 16
    float* redw = smem;            // 1024, used before staging (overlaps bt)

    // staging roles
    int brow = tid >> 3, bseg = tid & 7;   // bt: rows brow, brow+128; 8 segs of float4
    int hcc = tid & 15, hig = tid >> 4;    // ht: channel hcc, i-group hig (0..63, 4 i each)

    // issue chunk-0 prefetch FIRST; latency hides under the BN2 reduce
    float4 pb0, pb1, pc0;
    {
        pb0 = ((const float4*)(bmat + ((size_t)n * LEN + brow) * NODES + jbase))[bseg];
        pb1 = ((const float4*)(bmat + ((size_t)n * LEN + 128 + brow) * NODES + jbase))[bseg];
        pc0 = *(const float4*)(c2 + ((size_t)n * C2 + kbase + hcc) * LEN + hig * 4);
    }

    // BN2 reduce: 128 (s,q) values over 256 producer blocks; 8 groups x 32
    {
        int v = tid & 127, grp = tid >> 7;
        float a0=0,a1=0,a2=0,a3=0,a4=0,a5=0,a6=0,a7=0;
        int b0 = grp * 32;
        for (int i = 0; i < 32; i += 8) {
            a0 += s2p[(size_t)(b0+i  ) * 128 + v];
            a1 += s2p[(size_t)(b0+i+1) * 128 + v];
            a2 += s2p[(size_t)(b0+i+2) * 128 + v];
            a3 += s2p[(size_t)(b0+i+3) * 128 + v];
            a4 += s2p[(size_t)(b0+i+4) * 128 + v];
            a5 += s2p[(size_t)(b0+i+5) * 128 + v];
            a6 += s2p[(size_t)(b0+i+6) * 128 + v];
            a7 += s2p[(size_t)(b0+i+7) * 128 + v];
        }
        redw[grp * 128 + v] = ((a0+a1)+(a2+a3)) + ((a4+a5)+(a6+a7));
    }
    __syncthreads();
    if (tid < 128) {
        float s = redw[tid];
#pragma unroll
        for (int g = 1; g < 8; ++g) s += redw[g * 128 + tid];
        redw[tid] = s;
    }
    __syncthreads();
    if (tid < 16) {
        int c = kbase + tid;
        float s = redw[c * 2], q = redw[c * 2 + 1];
        float mean = s * (1.f / 16384.f);
        float var  = q * (1.f / 16384.f) - mean * mean;
        float rs   = rsqrtf(var + EPS);
        float sc   = g2[c] * rs;
        sc2s[tid] = sc;
        sh2s[tid] = bb2[c] - mean * sc;
    }
    __syncthreads();
    float scl = sc2s[hcc], shl = sh2s[hcc];

    // pool roles: lane&31 = combo (jq = combo>>2: 4 j's; kq = combo&3: 4 k's);
    // lane>>5 = i-half. Wave owns 16 rows/chunk; each lane does 8 of them.
    int jq = (lane & 31) >> 2, kq = lane & 3;
    int ibase0 = wave * 16 + (lane >> 5) * 8;
    float mx[4][4];
#pragma unroll
    for (int a = 0; a < 4; ++a)
#pragma unroll
        for (int c = 0; c < 4; ++c) mx[a][c] = 0.f;

    for (int it = 0; it < 4; ++it) {
        // write staged chunk from regs
        *(float4*)&bt[brow * 36 + bseg * 4] = pb0;
        *(float4*)&bt[(brow + 128) * 36 + bseg * 4] = pb1;
        {
            int i0 = hig * 4;
            ht[(i0 + 0) * 20 + hcc] = fmaxf(0.f, pc0.x * scl + shl);
            ht[(i0 + 1) * 20 + hcc] = fmaxf(0.f, pc0.y * scl + shl);
            ht[(i0 + 2) * 20 + hcc] = fmaxf(0.f, pc0.z * scl + shl);
            ht[(i0 + 3) * 20 + hcc] = fmaxf(0.f, pc0.w * scl + shl);
        }
        __syncthreads();
        if (it < 3) {   // prefetch next chunk; hides under pool loop
            int ib = (it + 1) * 256;
            pb0 = ((const float4*)(bmat + ((size_t)n * LEN + ib + brow) * NODES + jbase))[bseg];
            pb1 = ((const float4*)(bmat + ((size_t)n * LEN + ib + 128 + brow) * NODES + jbase))[bseg];
            pc0 = *(const float4*)(c2 + ((size_t)n * C2 + kbase + hcc) * LEN + ib + hig * 4);
        }
#pragma unroll 8
        for (int ii = 0; ii < 8; ++ii) {
            int i = ibase0 + ii;
            float4 bv = *(const float4*)&bt[i * 36 + jq * 4];
            float4 hv = *(const float4*)&ht[i * 20 + kq * 4];
            mx[0][0] = fmaxf(mx[0][0], bv.x * hv.x);
            mx[0][1] = fmaxf(mx[0][1], bv.x * hv.y);
            mx[0][2] = fmaxf(mx[0][2], bv.x * hv.z);
            mx[0][3] = fmaxf(mx[0][3], bv.x * hv.w);
            mx[1][0] = fmaxf(mx[1][0], bv.y * hv.x);
            mx[1][1] = fmaxf(mx[1][1], bv.y * hv.y);
            mx[1][2] = fmaxf(mx[1][2], bv.y * hv.z);
            mx[1][3] = fmaxf(mx[1][3], bv.y * hv.w);
            mx[2][0] = fmaxf(mx[2][0], bv.z * hv.x);
            mx[2][1] = fmaxf(mx[2][1], bv.z * hv.y);
            mx[2][2] = fmaxf(mx[2][2], bv.z * hv.z);
            mx[2][3] = fmaxf(mx[2][3], bv.z * hv.w);
            mx[3][0] = fmaxf(mx[3][0], bv.w * hv.x);
            mx[3][1] = fmaxf(mx[3][1], bv.w * hv.y);
            mx[3][2] = fmaxf(mx[3][2], bv.w * hv.z);
            mx[3][3] = fmaxf(mx[3][3], bv.w * hv.w);
        }
        __syncthreads();
    }

    // combine the two i-halves within the wave, then 16-way across waves
#pragma unroll
    for (int a = 0; a < 4; ++a)
#pragma unroll
        for (int c = 0; c < 4; ++c)
            mx[a][c] = fmaxf(mx[a][c], __shfl_xor(mx[a][c], 32));

    float* zpart = smem;            // 16 x 512 = 8192 (bt dead)
    float* zhalf = smem + 9216;     // 1024 (ht region)
    float* zsl   = smem + 10240;    // 512
    if (lane < 32) {
#pragma unroll
        for (int a = 0; a < 4; ++a)
            *(float4*)&zpart[wave * 512 + (jq * 4 + a) * 16 + kq * 4]
                = make_float4(mx[a][0], mx[a][1], mx[a][2], mx[a][3]);
    }
    __syncthreads();
    {
        int o = tid & 511, half = tid >> 9;
        int p0 = half * 8;
        float m = zpart[p0 * 512 + o];
#pragma unroll
        for (int p = 1; p < 8; ++p) m = fmaxf(m, zpart[(p0 + p) * 512 + o]);
        zhalf[half * 512 + o] = m;
    }
    __syncthreads();
    if (tid < 512) zsl[tid] = fmaxf(zhalf[tid], zhalf[512 + tid]);
    __syncthreads();

    // FC1 slice: 16 waves split 100 features (7,7,7,7,6x12); full-cacheline w1 reads
    {
        int slice = jt * 4 + ks;
        float4 za = *(const float4*)&zsl[lane * 8];
        float4 zb = *(const float4*)&zsl[lane * 8 + 4];
        int jloc = lane >> 1, kq2 = (lane & 1) * 8;
        const float* wb = w1 + (size_t)(jbase + jloc) * 64 + kbase + kq2;
        int f0 = (wave < 4) ? wave * 7 : 28 + (wave - 4) * 6;
        int nf = (wave < 4) ? 7 : 6;
        for (int t = 0; t < nf; ++t) {
            int f = f0 + t;
            const float* wp = wb + (size_t)f * 8192;
            float4 w0 = *(const float4*)wp;
            float4 w1v = *(const float4*)(wp + 4);
            float s = za.x * w0.x + za.y * w0.y + za.z * w0.z + za.w * w0.w
                    + zb.x * w1v.x + zb.y * w1v.y + zb.z * w1v.z + zb.w * w1v.w;
#pragma unroll
            for (int off = 32; off >= 1; off >>= 1) s += __shfl_xor(s, off);
            if (lane == 0)
                atomicExch(&zzp[(size_t)slice * 1600 + n * 100 + f], s);
        }
    }

    // 2-level ticket: drain own exchanges; last-of-16-per-n bumps global; last runs tail
    asm volatile("s_waitcnt vmcnt(0)" ::: "memory");
    __syncthreads();
    if (tid == 0) {
        sflag = 0u;
        if (atomicAdd(&cnt[1 + n], 1u) == 15u)
            if (atomicAdd(&cnt[0], 1u) == 15u) sflag = 1u;
    }
    __syncthreads();
    if (!sflag) return;

    // finisher: combine 16 zzp slices + b1, BN3 over batch, ReLU, FC2 -> out
    float* zzl = smem;          // 1600
    float* sc3 = smem + 1600;   // 100
    float* sh3 = smem + 1700;   // 100

    for (int t = tid; t < BATCH * NF1; t += 1024) {
        float a = 0.f;
#pragma unroll
        for (int sI = 0; sI < 16; ++sI) a += AL(&zzp[(size_t)sI * 1600 + t]);
        zzl[t] = a + b1f[t % NF1];
    }
    __syncthreads();
    if (tid < NF1) {
        float s = 0.f, q = 0.f;
#pragma unroll
        for (int m = 0; m < BATCH; ++m) {
            float v = zzl[m * NF1 + tid];
            s += v; q += v * v;
        }
        float mean = s * (1.f / 16.f);
        float var  = q * (1.f / 16.f) - mean * mean;
        float rs   = rsqrtf(var + EPS);
        float sc   = g3[tid] * rs;
        sc3[tid] = sc;
        sh3[tid] = b3[tid] - mean * sc;
    }
    __syncthreads();
    for (int t = tid; t < BATCH * NF1; t += 1024) {
        int f = t % NF1;
        zzl[t] = fmaxf(0.f, zzl[t] * sc3[f] + sh3[f]);
    }
    __syncthreads();
    {
        int o = tid & 127, grp = tid >> 7;   // 8 groups x 2 batch rows
        float acc0 = b2f[o], acc1 = b2f[o];
        const float* wr = w2 + (size_t)o * NF1;
        for (int f = 0; f < NF1; ++f) {
            float wv = wr[f];
            acc0 += zzl[(grp * 2 + 0) * NF1 + f] * wv;
            acc1 += zzl[(grp * 2 + 1) * NF1 + f] * wv;
        }
        out[(grp * 2 + 0) * NF2 + o] = acc0;
        out[(grp * 2 + 1) * NF2 + o] = acc1;
    }
}

extern "C" void kernel_launch(void* const* d_in, const int* in_sizes, int n_in,
                              void* d_out, int out_size, void* d_ws, size_t ws_size,
                              hipStream_t stream) {
    const float* x    = (const float*)d_in[0];
    const float* bmat = (const float*)d_in[1];
    const float* c1w  = (const float*)d_in[2];
    const float* c1b  = (const float*)d_in[3];
    const float* g1   = (const float*)d_in[4];
    const float* bb1  = (const float*)d_in[5];
    const float* c2w  = (const float*)d_in[6];
    const float* c2b  = (const float*)d_in[7];
    const float* g2   = (const float*)d_in[8];
    const float* bb2  = (const float*)d_in[9];
    const float* w1   = (const float*)d_in[10];
    const float* b1   = (const float*)d_in[11];
    const float* g3   = (const float*)d_in[12];
    const float* b3   = (const float*)d_in[13];
    const float* w2   = (const float*)d_in[14];
    const float* b2   = (const float*)d_in[15];
    float* out = (float*)d_out;
    float* ws  = (float*)d_ws;

    float*    c1  = ws + OFF_C1;
    float*    c2  = ws + OFF_C2;
    float*    s1p = ws + OFF_S1P;
    float*    s2p = ws + OFF_S2P;
    float*    zzp = ws + OFF_ZZP;
    unsigned* cnt = (unsigned*)(ws + OFF_CNT);

    kA<<<256, 256, 0, stream>>>(x, c1w, c1b, c1, s1p);
    kB<<<256, 256, 0, stream>>>(c1, c2w, c2b, g1, bb1, s1p, c2, s2p, cnt);
    kC<<<256, 1024, 0, stream>>>(bmat, c2, g2, bb2, s2p, w1, b1, g3, b3, w2, b2,
                                 zzp, cnt, out);
}

// Round 11
// 141.553 us; speedup vs baseline: 1.0559x; 1.0559x over previous
//
#include <hip/hip_runtime.h>

#define EPS 1e-5f

#define BATCH 16
#define LEN   1024
#define C0    8
#define C1    32
#define C2    64
#define NODES 128
#define NF1   100
#define NF2   128

// workspace layout (float offsets) — round-6 proven. cnt[0..16] zeroed by kB
// (visible to kC via dispatch boundary); zzp fully written before read.
#define OFF_C1   0          // 16*32*1024 = 524288
#define OFF_C2   524288     // 16*64*1024 = 1048576
#define OFF_S1P  1572864    // 256 blocks * 64
#define OFF_S2P  1589248    // 256 blocks * 128
#define OFF_ZZP  1622016    // 16 slices * 16 n * 100 f = 25600
#define OFF_CNT  1647616    // 17 uints: [0]=global, [1+n]=per-n

#define AL(p) __hip_atomic_load((p), __ATOMIC_RELAXED, __HIP_MEMORY_SCOPE_AGENT)

// ---------------- kA: conv1 (8->32, K=5, pad 2) + bias -> c1, BN1 block partials
__global__ __launch_bounds__(256)
void kA(const float* __restrict__ x, const float* __restrict__ w,
        const float* __restrict__ bias, float* __restrict__ c1,
        float* __restrict__ s1p) {
    int tid = threadIdx.x, b = blockIdx.x;
    int lane = tid & 63, wave = tid >> 6;
    int n = b >> 4, lt = b & 15;
    int l = lt * 64 + lane;
    int cg8 = __builtin_amdgcn_readfirstlane(wave * 8);

    float xr[5][8];
#pragma unroll
    for (int dl = 0; dl < 5; ++dl) {
        int lw = l + dl - 2;
        if (lw >= 0 && lw < LEN) {
            const float4* p = (const float4*)(x + ((size_t)n * LEN + lw) * C0);
            float4 a = p[0], b4 = p[1];
            xr[dl][0] = a.x;  xr[dl][1] = a.y;  xr[dl][2] = a.z;  xr[dl][3] = a.w;
            xr[dl][4] = b4.x; xr[dl][5] = b4.y; xr[dl][6] = b4.z; xr[dl][7] = b4.w;
        } else {
#pragma unroll
            for (int ci = 0; ci < 8; ++ci) xr[dl][ci] = 0.f;
        }
    }
#pragma unroll
    for (int u = 0; u < 8; ++u) {
        int c = cg8 + u;
        float acc = bias[c];
        const float* wc = w + c * 40;
#pragma unroll
        for (int ci = 0; ci < 8; ++ci)
#pragma unroll
            for (int dl = 0; dl < 5; ++dl)
                acc += xr[dl][ci] * wc[ci * 5 + dl];
        c1[((size_t)n * C1 + c) * LEN + l] = acc;

        float s = acc, q = acc * acc;
#pragma unroll
        for (int off = 32; off >= 1; off >>= 1) {
            s += __shfl_xor(s, off);
            q += __shfl_xor(q, off);
        }
        if (lane == 0) {
            s1p[b * 64 + c * 2]     = s;
            s1p[b * 64 + c * 2 + 1] = q;
        }
    }
}

// ---------------- kB: 512 threads (2 waves/SIMD). BN1 reduce; BN1+ReLU ->
// conv2 (8 ch/wave) -> c2, BN2 partials; zero cnt
__global__ __launch_bounds__(512)
void kB(const float* __restrict__ c1, const float* __restrict__ w,
        const float* __restrict__ bias,
        const float* __restrict__ g1, const float* __restrict__ bb1,
        const float* __restrict__ s1p,
        float* __restrict__ c2, float* __restrict__ s2p,
        unsigned* __restrict__ cnt) {
    int tid = threadIdx.x, b = blockIdx.x;
    int lane = tid & 63, wave = tid >> 6;          // 8 waves

    if (b == 0 && tid < 17) cnt[tid] = 0u;

    __shared__ float sc1[32], sh1[32];
    __shared__ __align__(16) float a1[32 * 68];
    __shared__ float redw[512];

    // BN1 reduce: group g = wave (8 groups x 32 producer blocks), value = lane
    {
        float a0=0,a1_=0,a2=0,a3=0,a4=0,a5=0,a6=0,a7=0;
        int b0 = wave * 32;
        for (int i = 0; i < 32; i += 8) {
            a0  += s1p[(size_t)(b0+i  ) * 64 + lane];
            a1_ += s1p[(size_t)(b0+i+1) * 64 + lane];
            a2  += s1p[(size_t)(b0+i+2) * 64 + lane];
            a3  += s1p[(size_t)(b0+i+3) * 64 + lane];
            a4  += s1p[(size_t)(b0+i+4) * 64 + lane];
            a5  += s1p[(size_t)(b0+i+5) * 64 + lane];
            a6  += s1p[(size_t)(b0+i+6) * 64 + lane];
            a7  += s1p[(size_t)(b0+i+7) * 64 + lane];
        }
        redw[wave * 64 + lane] = ((a0+a1_)+(a2+a3)) + ((a4+a5)+(a6+a7));
    }
    __syncthreads();
    if (tid < 64) {
        float s = redw[tid];
#pragma unroll
        for (int g = 1; g < 8; ++g) s += redw[g * 64 + tid];
        redw[tid] = s;
    }
    __syncthreads();
    if (tid < 32) {
        float s = redw[tid * 2], q = redw[tid * 2 + 1];
        float mean = s * (1.f / 16384.f);
        float var  = q * (1.f / 16384.f) - mean * mean;
        float rs   = rsqrtf(var + EPS);
        float sc   = g1[tid] * rs;
        sc1[tid] = sc;
        sh1[tid] = bb1[tid] - mean * sc;
    }
    __syncthreads();

    int n = b >> 4, lt = b & 15;
    int lbase = lt * 64;

    for (int idx = tid; idx < 32 * 68; idx += 512) {
        int ci = idx / 68, lo = idx - ci * 68;
        int lg = lbase + lo - 2;
        float v = 0.f;
        if (lg >= 0 && lg < LEN) v = c1[((size_t)n * C1 + ci) * LEN + lg];
        a1[idx] = fmaxf(0.f, v * sc1[ci] + sh1[ci]);
    }
    __syncthreads();

    int l = lane;
    int cobase = __builtin_amdgcn_readfirstlane(wave * 8);   // 8 channels/wave

    float acc[8];
#pragma unroll
    for (int u = 0; u < 8; ++u) acc[u] = bias[cobase + u];

    for (int ci = 0; ci < 32; ++ci) {
        float v0 = a1[ci * 68 + l + 0];
        float v1 = a1[ci * 68 + l + 1];
        float v2 = a1[ci * 68 + l + 2];
        float v3 = a1[ci * 68 + l + 3];
        float v4 = a1[ci * 68 + l + 4];
#pragma unroll
        for (int u = 0; u < 8; ++u) {
            const float* wp = w + ((size_t)(cobase + u) * 32 + ci) * 5;
            acc[u] += v0 * wp[0] + v1 * wp[1] + v2 * wp[2] + v3 * wp[3] + v4 * wp[4];
        }
    }

    int lg = lbase + l;
#pragma unroll
    for (int u = 0; u < 8; ++u)
        c2[((size_t)n * C2 + cobase + u) * LEN + lg] = acc[u];

    for (int u = 0; u < 8; ++u) {
        float s = acc[u], q = acc[u] * acc[u];
#pragma unroll
        for (int off = 32; off >= 1; off >>= 1) {
            s += __shfl_xor(s, off);
            q += __shfl_xor(q, off);
        }
        if (lane == 0) {
            int c = cobase + u;
            s2p[b * 128 + c * 2]     = s;
            s2p[b * 128 + c * 2 + 1] = q;
        }
    }
}

// ---------------- kC: 256 blocks x 1024 threads. BN2 reduce; pool (4j x 4k per
// lane, shfl-combined i-halves); FC1 slice -> zzp; 2-level ticket -> BN3+FC2
__global__ __launch_bounds__(1024)
void kC(const float* __restrict__ bmat, const float* __restrict__ c2,
        const float* __restrict__ g2, const float* __restrict__ bb2,
        const float* __restrict__ s2p, const float* __restrict__ w1,
        const float* __restrict__ b1f, const float* __restrict__ g3,
        const float* __restrict__ b3, const float* __restrict__ w2,
        const float* __restrict__ b2f,
        float* __restrict__ zzp, unsigned* __restrict__ cnt,
        float* __restrict__ out) {
    int tid = threadIdx.x, b = blockIdx.x;
    int lane = tid & 63, wave = tid >> 6;          // 16 waves
    int n = b >> 4, jt = (b >> 2) & 3, ks = b & 3;
    int jbase = jt * 32, kbase = ks * 16;

    __shared__ __align__(16) float smem[14368];
    __shared__ unsigned sflag;
    float* bt   = smem;            // 256 x 36 = 9216
    float* ht   = smem + 9216;     // 256 x 20 = 5120 -> 14336
    float* sc2s = smem + 14336;    // 16
    float* sh2s = smem + 14352;    // 16
    float* redw = smem;            // 1024, used before staging (overlaps bt)

    // staging roles
    int brow = tid >> 3, bseg = tid & 7;   // bt: rows brow, brow+128; 8 segs of float4
    int hcc = tid & 15, hig = tid >> 4;    // ht: channel hcc, i-group hig (0..63, 4 i each)

    // issue chunk-0 prefetch FIRST; latency hides under the BN2 reduce
    float4 pb0, pb1, pc0;
    {
        pb0 = ((const float4*)(bmat + ((size_t)n * LEN + brow) * NODES + jbase))[bseg];
        pb1 = ((const float4*)(bmat + ((size_t)n * LEN + 128 + brow) * NODES + jbase))[bseg];
        pc0 = *(const float4*)(c2 + ((size_t)n * C2 + kbase + hcc) * LEN + hig * 4);
    }

    // BN2 reduce: 128 (s,q) values over 256 producer blocks; 8 groups x 32
    {
        int v = tid & 127, grp = tid >> 7;
        float a0=0,a1=0,a2=0,a3=0,a4=0,a5=0,a6=0,a7=0;
        int b0 = grp * 32;
        for (int i = 0; i < 32; i += 8) {
            a0 += s2p[(size_t)(b0+i  ) * 128 + v];
            a1 += s2p[(size_t)(b0+i+1) * 128 + v];
            a2 += s2p[(size_t)(b0+i+2) * 128 + v];
            a3 += s2p[(size_t)(b0+i+3) * 128 + v];
            a4 += s2p[(size_t)(b0+i+4) * 128 + v];
            a5 += s2p[(size_t)(b0+i+5) * 128 + v];
            a6 += s2p[(size_t)(b0+i+6) * 128 + v];
            a7 += s2p[(size_t)(b0+i+7) * 128 + v];
        }
        redw[grp * 128 + v] = ((a0+a1)+(a2+a3)) + ((a4+a5)+(a6+a7));
    }
    __syncthreads();
    if (tid < 128) {
        float s = redw[tid];
#pragma unroll
        for (int g = 1; g < 8; ++g) s += redw[g * 128 + tid];
        redw[tid] = s;
    }
    __syncthreads();
    if (tid < 16) {
        int c = kbase + tid;
        float s = redw[c * 2], q = redw[c * 2 + 1];
        float mean = s * (1.f / 16384.f);
        float var  = q * (1.f / 16384.f) - mean * mean;
        float rs   = rsqrtf(var + EPS);
        float sc   = g2[c] * rs;
        sc2s[tid] = sc;
        sh2s[tid] = bb2[c] - mean * sc;
    }
    __syncthreads();
    float scl = sc2s[hcc], shl = sh2s[hcc];

    // pool roles: lane&31 = combo (jq = combo>>2: 4 j's; kq = combo&3: 4 k's);
    // lane>>5 = i-half. Wave owns 16 rows/chunk; each lane does 8 of them.
    int jq = (lane & 31) >> 2, kq = lane & 3;
    int ibase0 = wave * 16 + (lane >> 5) * 8;
    float mx[4][4];
#pragma unroll
    for (int a = 0; a < 4; ++a)
#pragma unroll
        for (int c = 0; c < 4; ++c) mx[a][c] = 0.f;

    for (int it = 0; it < 4; ++it) {
        // write staged chunk from regs
        *(float4*)&bt[brow * 36 + bseg * 4] = pb0;
        *(float4*)&bt[(brow + 128) * 36 + bseg * 4] = pb1;
        {
            int i0 = hig * 4;
            ht[(i0 + 0) * 20 + hcc] = fmaxf(0.f, pc0.x * scl + shl);
            ht[(i0 + 1) * 20 + hcc] = fmaxf(0.f, pc0.y * scl + shl);
            ht[(i0 + 2) * 20 + hcc] = fmaxf(0.f, pc0.z * scl + shl);
            ht[(i0 + 3) * 20 + hcc] = fmaxf(0.f, pc0.w * scl + shl);
        }
        __syncthreads();
        if (it < 3) {   // prefetch next chunk; hides under pool loop
            int ib = (it + 1) * 256;
            pb0 = ((const float4*)(bmat + ((size_t)n * LEN + ib + brow) * NODES + jbase))[bseg];
            pb1 = ((const float4*)(bmat + ((size_t)n * LEN + ib + 128 + brow) * NODES + jbase))[bseg];
            pc0 = *(const float4*)(c2 + ((size_t)n * C2 + kbase + hcc) * LEN + ib + hig * 4);
        }
#pragma unroll 8
        for (int ii = 0; ii < 8; ++ii) {
            int i = ibase0 + ii;
            float4 bv = *(const float4*)&bt[i * 36 + jq * 4];
            float4 hv = *(const float4*)&ht[i * 20 + kq * 4];
            mx[0][0] = fmaxf(mx[0][0], bv.x * hv.x);
            mx[0][1] = fmaxf(mx[0][1], bv.x * hv.y);
            mx[0][2] = fmaxf(mx[0][2], bv.x * hv.z);
            mx[0][3] = fmaxf(mx[0][3], bv.x * hv.w);
            mx[1][0] = fmaxf(mx[1][0], bv.y * hv.x);
            mx[1][1] = fmaxf(mx[1][1], bv.y * hv.y);
            mx[1][2] = fmaxf(mx[1][2], bv.y * hv.z);
            mx[1][3] = fmaxf(mx[1][3], bv.y * hv.w);
            mx[2][0] = fmaxf(mx[2][0], bv.z * hv.x);
            mx[2][1] = fmaxf(mx[2][1], bv.z * hv.y);
            mx[2][2] = fmaxf(mx[2][2], bv.z * hv.z);
            mx[2][3] = fmaxf(mx[2][3], bv.z * hv.w);
            mx[3][0] = fmaxf(mx[3][0], bv.w * hv.x);
            mx[3][1] = fmaxf(mx[3][1], bv.w * hv.y);
            mx[3][2] = fmaxf(mx[3][2], bv.w * hv.z);
            mx[3][3] = fmaxf(mx[3][3], bv.w * hv.w);
        }
        __syncthreads();
    }

    // combine the two i-halves within the wave, then direct 16-way across waves
#pragma unroll
    for (int a = 0; a < 4; ++a)
#pragma unroll
        for (int c = 0; c < 4; ++c)
            mx[a][c] = fmaxf(mx[a][c], __shfl_xor(mx[a][c], 32));

    float* zpart = smem;            // 16 x 512 = 8192 (bt dead)
    float* zsl   = smem + 9216;     // 512 (ht region)
    if (lane < 32) {
#pragma unroll
        for (int a = 0; a < 4; ++a)
            *(float4*)&zpart[wave * 512 + (jq * 4 + a) * 16 + kq * 4]
                = make_float4(mx[a][0], mx[a][1], mx[a][2], mx[a][3]);
    }
    __syncthreads();
    if (tid < 512) {
        float m = zpart[tid];
#pragma unroll
        for (int p = 1; p < 16; ++p) m = fmaxf(m, zpart[p * 512 + tid]);
        zsl[tid] = m;
    }
    __syncthreads();

    // FC1 slice: 16 waves split 100 features (7,7,7,7,6x12); full-cacheline w1 reads
    {
        int slice = jt * 4 + ks;
        float4 za = *(const float4*)&zsl[lane * 8];
        float4 zb = *(const float4*)&zsl[lane * 8 + 4];
        int jloc = lane >> 1, kq2 = (lane & 1) * 8;
        const float* wb = w1 + (size_t)(jbase + jloc) * 64 + kbase + kq2;
        int f0 = (wave < 4) ? wave * 7 : 28 + (wave - 4) * 6;
        int nf = (wave < 4) ? 7 : 6;
        for (int t = 0; t < nf; ++t) {
            int f = f0 + t;
            const float* wp = wb + (size_t)f * 8192;
            float4 w0 = *(const float4*)wp;
            float4 w1v = *(const float4*)(wp + 4);
            float s = za.x * w0.x + za.y * w0.y + za.z * w0.z + za.w * w0.w
                    + zb.x * w1v.x + zb.y * w1v.y + zb.z * w1v.z + zb.w * w1v.w;
#pragma unroll
            for (int off = 32; off >= 1; off >>= 1) s += __shfl_xor(s, off);
            if (lane == 0)
                atomicExch(&zzp[(size_t)slice * 1600 + n * 100 + f], s);
        }
    }

    // 2-level ticket: drain own exchanges; last-of-16-per-n bumps global; last runs tail
    asm volatile("s_waitcnt vmcnt(0)" ::: "memory");
    __syncthreads();
    if (tid == 0) {
        sflag = 0u;
        if (atomicAdd(&cnt[1 + n], 1u) == 15u)
            if (atomicAdd(&cnt[0], 1u) == 15u) sflag = 1u;
    }
    __syncthreads();
    if (!sflag) return;

    // finisher: combine 16 zzp slices + b1, BN3 over batch, ReLU, FC2 -> out
    float* zzl = smem;          // 1600
    float* sc3 = smem + 1600;   // 100
    float* sh3 = smem + 1700;   // 100

    for (int t = tid; t < BATCH * NF1; t += 1024) {
        float a = 0.f;
#pragma unroll
        for (int sI = 0; sI < 16; ++sI) a += AL(&zzp[(size_t)sI * 1600 + t]);
        zzl[t] = a + b1f[t % NF1];
    }
    __syncthreads();
    if (tid < NF1) {
        float s = 0.f, q = 0.f;
#pragma unroll
        for (int m = 0; m < BATCH; ++m) {
            float v = zzl[m * NF1 + tid];
            s += v; q += v * v;
        }
        float mean = s * (1.f / 16.f);
        float var  = q * (1.f / 16.f) - mean * mean;
        float rs   = rsqrtf(var + EPS);
        float sc   = g3[tid] * rs;
        sc3[tid] = sc;
        sh3[tid] = b3[tid] - mean * sc;
    }
    __syncthreads();
    for (int t = tid; t < BATCH * NF1; t += 1024) {
        int f = t % NF1;
        zzl[t] = fmaxf(0.f, zzl[t] * sc3[f] + sh3[f]);
    }
    __syncthreads();
    {
        int o = tid & 127, grp = tid >> 7;   // 8 groups x 2 batch rows
        float acc0 = b2f[o], acc1 = b2f[o];
        const float* wr = w2 + (size_t)o * NF1;
        for (int f = 0; f < NF1; ++f) {
            float wv = wr[f];
            acc0 += zzl[(grp * 2 + 0) * NF1 + f] * wv;
            acc1 += zzl[(grp * 2 + 1) * NF1 + f] * wv;
        }
        out[(grp * 2 + 0) * NF2 + o] = acc0;
        out[(grp * 2 + 1) * NF2 + o] = acc1;
    }
}

extern "C" void kernel_launch(void* const* d_in, const int* in_sizes, int n_in,
                              void* d_out, int out_size, void* d_ws, size_t ws_size,
                              hipStream_t stream) {
    const float* x    = (const float*)d_in[0];
    const float* bmat = (const float*)d_in[1];
    const float* c1w  = (const float*)d_in[2];
    const float* c1b  = (const float*)d_in[3];
    const float* g1   = (const float*)d_in[4];
    const float* bb1  = (const float*)d_in[5];
    const float* c2w  = (const float*)d_in[6];
    const float* c2b  = (const float*)d_in[7];
    const float* g2   = (const float*)d_in[8];
    const float* bb2  = (const float*)d_in[9];
    const float* w1   = (const float*)d_in[10];
    const float* b1   = (const float*)d_in[11];
    const float* g3   = (const float*)d_in[12];
    const float* b3   = (const float*)d_in[13];
    const float* w2   = (const float*)d_in[14];
    const float* b2   = (const float*)d_in[15];
    float* out = (float*)d_out;
    float* ws  = (float*)d_ws;

    float*    c1  = ws + OFF_C1;
    float*    c2  = ws + OFF_C2;
    float*    s1p = ws + OFF_S1P;
    float*    s2p = ws + OFF_S2P;
    float*    zzp = ws + OFF_ZZP;
    unsigned* cnt = (unsigned*)(ws + OFF_CNT);

    kA<<<256, 256, 0, stream>>>(x, c1w, c1b, c1, s1p);
    kB<<<256, 512, 0, stream>>>(c1, c2w, c2b, g1, bb1, s1p, c2, s2p, cnt);
    kC<<<256, 1024, 0, stream>>>(bmat, c2, g2, bb2, s2p, w1, b1, g3, b3, w2, b2,
                                 zzp, cnt, out);
}

// Round 12
// 137.244 us; speedup vs baseline: 1.0890x; 1.0314x over previous
//
#include <hip/hip_runtime.h>

#define EPS 1e-5f

#define BATCH 16
#define LEN   1024
#define C0    8
#define C1    32
#define C2    64
#define NODES 128
#define NF1   100
#define NF2   128

// workspace layout (float offsets) — round-6 proven. cnt[0..16] zeroed by kB
// (visible to kC via dispatch boundary); zzp fully written before read.
#define OFF_C1   0          // 16*32*1024 = 524288
#define OFF_C2   524288     // 16*64*1024 = 1048576
#define OFF_S1P  1572864    // 256 blocks * 64
#define OFF_S2P  1589248    // 256 blocks * 128
#define OFF_ZZP  1622016    // 16 slices * 16 n * 100 f = 25600
#define OFF_CNT  1647616    // 17 uints: [0]=global, [1+n]=per-n

#define AL(p) __hip_atomic_load((p), __ATOMIC_RELAXED, __HIP_MEMORY_SCOPE_AGENT)

// ---------------- kA: 512 threads (2 waves/SIMD). conv1 (8->32, K=5, pad 2)
// + bias -> c1, BN1 block partials (4 channels/wave)
__global__ __launch_bounds__(512)
void kA(const float* __restrict__ x, const float* __restrict__ w,
        const float* __restrict__ bias, float* __restrict__ c1,
        float* __restrict__ s1p) {
    int tid = threadIdx.x, b = blockIdx.x;
    int lane = tid & 63, wave = tid >> 6;          // 8 waves
    int n = b >> 4, lt = b & 15;
    int l = lt * 64 + lane;
    int cg4 = __builtin_amdgcn_readfirstlane(wave * 4);   // 4 channels/wave

    float xr[5][8];
#pragma unroll
    for (int dl = 0; dl < 5; ++dl) {
        int lw = l + dl - 2;
        if (lw >= 0 && lw < LEN) {
            const float4* p = (const float4*)(x + ((size_t)n * LEN + lw) * C0);
            float4 a = p[0], b4 = p[1];
            xr[dl][0] = a.x;  xr[dl][1] = a.y;  xr[dl][2] = a.z;  xr[dl][3] = a.w;
            xr[dl][4] = b4.x; xr[dl][5] = b4.y; xr[dl][6] = b4.z; xr[dl][7] = b4.w;
        } else {
#pragma unroll
            for (int ci = 0; ci < 8; ++ci) xr[dl][ci] = 0.f;
        }
    }
#pragma unroll
    for (int u = 0; u < 4; ++u) {
        int c = cg4 + u;
        float acc = bias[c];
        const float* wc = w + c * 40;
#pragma unroll
        for (int ci = 0; ci < 8; ++ci)
#pragma unroll
            for (int dl = 0; dl < 5; ++dl)
                acc += xr[dl][ci] * wc[ci * 5 + dl];
        c1[((size_t)n * C1 + c) * LEN + l] = acc;

        float s = acc, q = acc * acc;
#pragma unroll
        for (int off = 32; off >= 1; off >>= 1) {
            s += __shfl_xor(s, off);
            q += __shfl_xor(q, off);
        }
        if (lane == 0) {
            s1p[b * 64 + c * 2]     = s;
            s1p[b * 64 + c * 2 + 1] = q;
        }
    }
}

// ---------------- kB: 512 threads (2 waves/SIMD). BN1 reduce; BN1+ReLU ->
// conv2 (8 ch/wave) -> c2, BN2 partials; zero cnt
__global__ __launch_bounds__(512)
void kB(const float* __restrict__ c1, const float* __restrict__ w,
        const float* __restrict__ bias,
        const float* __restrict__ g1, const float* __restrict__ bb1,
        const float* __restrict__ s1p,
        float* __restrict__ c2, float* __restrict__ s2p,
        unsigned* __restrict__ cnt) {
    int tid = threadIdx.x, b = blockIdx.x;
    int lane = tid & 63, wave = tid >> 6;          // 8 waves

    if (b == 0 && tid < 17) cnt[tid] = 0u;

    __shared__ float sc1[32], sh1[32];
    __shared__ __align__(16) float a1[32 * 68];
    __shared__ float redw[512];

    // BN1 reduce: group g = wave (8 groups x 32 producer blocks), value = lane
    {
        float a0=0,a1_=0,a2=0,a3=0,a4=0,a5=0,a6=0,a7=0;
        int b0 = wave * 32;
        for (int i = 0; i < 32; i += 8) {
            a0  += s1p[(size_t)(b0+i  ) * 64 + lane];
            a1_ += s1p[(size_t)(b0+i+1) * 64 + lane];
            a2  += s1p[(size_t)(b0+i+2) * 64 + lane];
            a3  += s1p[(size_t)(b0+i+3) * 64 + lane];
            a4  += s1p[(size_t)(b0+i+4) * 64 + lane];
            a5  += s1p[(size_t)(b0+i+5) * 64 + lane];
            a6  += s1p[(size_t)(b0+i+6) * 64 + lane];
            a7  += s1p[(size_t)(b0+i+7) * 64 + lane];
        }
        redw[wave * 64 + lane] = ((a0+a1_)+(a2+a3)) + ((a4+a5)+(a6+a7));
    }
    __syncthreads();
    if (tid < 64) {
        float s = redw[tid];
#pragma unroll
        for (int g = 1; g < 8; ++g) s += redw[g * 64 + tid];
        redw[tid] = s;
    }
    __syncthreads();
    if (tid < 32) {
        float s = redw[tid * 2], q = redw[tid * 2 + 1];
        float mean = s * (1.f / 16384.f);
        float var  = q * (1.f / 16384.f) - mean * mean;
        float rs   = rsqrtf(var + EPS);
        float sc   = g1[tid] * rs;
        sc1[tid] = sc;
        sh1[tid] = bb1[tid] - mean * sc;
    }
    __syncthreads();

    int n = b >> 4, lt = b & 15;
    int lbase = lt * 64;

    for (int idx = tid; idx < 32 * 68; idx += 512) {
        int ci = idx / 68, lo = idx - ci * 68;
        int lg = lbase + lo - 2;
        float v = 0.f;
        if (lg >= 0 && lg < LEN) v = c1[((size_t)n * C1 + ci) * LEN + lg];
        a1[idx] = fmaxf(0.f, v * sc1[ci] + sh1[ci]);
    }
    __syncthreads();

    int l = lane;
    int cobase = __builtin_amdgcn_readfirstlane(wave * 8);   // 8 channels/wave

    float acc[8];
#pragma unroll
    for (int u = 0; u < 8; ++u) acc[u] = bias[cobase + u];

    for (int ci = 0; ci < 32; ++ci) {
        float v0 = a1[ci * 68 + l + 0];
        float v1 = a1[ci * 68 + l + 1];
        float v2 = a1[ci * 68 + l + 2];
        float v3 = a1[ci * 68 + l + 3];
        float v4 = a1[ci * 68 + l + 4];
#pragma unroll
        for (int u = 0; u < 8; ++u) {
            const float* wp = w + ((size_t)(cobase + u) * 32 + ci) * 5;
            acc[u] += v0 * wp[0] + v1 * wp[1] + v2 * wp[2] + v3 * wp[3] + v4 * wp[4];
        }
    }

    int lg = lbase + l;
#pragma unroll
    for (int u = 0; u < 8; ++u)
        c2[((size_t)n * C2 + cobase + u) * LEN + lg] = acc[u];

    for (int u = 0; u < 8; ++u) {
        float s = acc[u], q = acc[u] * acc[u];
#pragma unroll
        for (int off = 32; off >= 1; off >>= 1) {
            s += __shfl_xor(s, off);
            q += __shfl_xor(q, off);
        }
        if (lane == 0) {
            int c = cobase + u;
            s2p[b * 128 + c * 2]     = s;
            s2p[b * 128 + c * 2 + 1] = q;
        }
    }
}

// ---------------- kC: 256 blocks x 1024 threads. BN2 reduce; pool (4j x 4k per
// lane, shfl-combined i-halves); FC1 slice -> zzp; 2-level ticket -> BN3+FC2
__global__ __launch_bounds__(1024)
void kC(const float* __restrict__ bmat, const float* __restrict__ c2,
        const float* __restrict__ g2, const float* __restrict__ bb2,
        const float* __restrict__ s2p, const float* __restrict__ w1,
        const float* __restrict__ b1f, const float* __restrict__ g3,
        const float* __restrict__ b3, const float* __restrict__ w2,
        const float* __restrict__ b2f,
        float* __restrict__ zzp, unsigned* __restrict__ cnt,
        float* __restrict__ out) {
    int tid = threadIdx.x, b = blockIdx.x;
    int lane = tid & 63, wave = tid >> 6;          // 16 waves
    int n = b >> 4, jt = (b >> 2) & 3, ks = b & 3;
    int jbase = jt * 32, kbase = ks * 16;

    __shared__ __align__(16) float smem[14368];
    __shared__ unsigned sflag;
    float* bt   = smem;            // 256 x 36 = 9216
    float* ht   = smem + 9216;     // 256 x 20 = 5120 -> 14336
    float* sc2s = smem + 14336;    // 16
    float* sh2s = smem + 14352;    // 16
    float* redw = smem;            // 1024, used before staging (overlaps bt)

    // staging roles
    int brow = tid >> 3, bseg = tid & 7;   // bt: rows brow, brow+128; 8 segs of float4
    int hcc = tid & 15, hig = tid >> 4;    // ht: channel hcc, i-group hig (0..63, 4 i each)

    // issue chunk-0 prefetch FIRST; latency hides under the BN2 reduce
    float4 pb0, pb1, pc0;
    {
        pb0 = ((const float4*)(bmat + ((size_t)n * LEN + brow) * NODES + jbase))[bseg];
        pb1 = ((const float4*)(bmat + ((size_t)n * LEN + 128 + brow) * NODES + jbase))[bseg];
        pc0 = *(const float4*)(c2 + ((size_t)n * C2 + kbase + hcc) * LEN + hig * 4);
    }

    // BN2 reduce: 128 (s,q) values over 256 producer blocks; 8 groups x 32
    {
        int v = tid & 127, grp = tid >> 7;
        float a0=0,a1=0,a2=0,a3=0,a4=0,a5=0,a6=0,a7=0;
        int b0 = grp * 32;
        for (int i = 0; i < 32; i += 8) {
            a0 += s2p[(size_t)(b0+i  ) * 128 + v];
            a1 += s2p[(size_t)(b0+i+1) * 128 + v];
            a2 += s2p[(size_t)(b0+i+2) * 128 + v];
            a3 += s2p[(size_t)(b0+i+3) * 128 + v];
            a4 += s2p[(size_t)(b0+i+4) * 128 + v];
            a5 += s2p[(size_t)(b0+i+5) * 128 + v];
            a6 += s2p[(size_t)(b0+i+6) * 128 + v];
            a7 += s2p[(size_t)(b0+i+7) * 128 + v];
        }
        redw[grp * 128 + v] = ((a0+a1)+(a2+a3)) + ((a4+a5)+(a6+a7));
    }
    __syncthreads();
    if (tid < 128) {
        float s = redw[tid];
#pragma unroll
        for (int g = 1; g < 8; ++g) s += redw[g * 128 + tid];
        redw[tid] = s;
    }
    __syncthreads();
    if (tid < 16) {
        int c = kbase + tid;
        float s = redw[c * 2], q = redw[c * 2 + 1];
        float mean = s * (1.f / 16384.f);
        float var  = q * (1.f / 16384.f) - mean * mean;
        float rs   = rsqrtf(var + EPS);
        float sc   = g2[c] * rs;
        sc2s[tid] = sc;
        sh2s[tid] = bb2[c] - mean * sc;
    }
    __syncthreads();
    float scl = sc2s[hcc], shl = sh2s[hcc];

    // pool roles: lane&31 = combo (jq = combo>>2: 4 j's; kq = combo&3: 4 k's);
    // lane>>5 = i-half. Wave owns 16 rows/chunk; each lane does 8 of them.
    int jq = (lane & 31) >> 2, kq = lane & 3;
    int ibase0 = wave * 16 + (lane >> 5) * 8;
    float mx[4][4];
#pragma unroll
    for (int a = 0; a < 4; ++a)
#pragma unroll
        for (int c = 0; c < 4; ++c) mx[a][c] = 0.f;

    for (int it = 0; it < 4; ++it) {
        // write staged chunk from regs
        *(float4*)&bt[brow * 36 + bseg * 4] = pb0;
        *(float4*)&bt[(brow + 128) * 36 + bseg * 4] = pb1;
        {
            int i0 = hig * 4;
            ht[(i0 + 0) * 20 + hcc] = fmaxf(0.f, pc0.x * scl + shl);
            ht[(i0 + 1) * 20 + hcc] = fmaxf(0.f, pc0.y * scl + shl);
            ht[(i0 + 2) * 20 + hcc] = fmaxf(0.f, pc0.z * scl + shl);
            ht[(i0 + 3) * 20 + hcc] = fmaxf(0.f, pc0.w * scl + shl);
        }
        __syncthreads();
        if (it < 3) {   // prefetch next chunk; hides under pool loop
            int ib = (it + 1) * 256;
            pb0 = ((const float4*)(bmat + ((size_t)n * LEN + ib + brow) * NODES + jbase))[bseg];
            pb1 = ((const float4*)(bmat + ((size_t)n * LEN + ib + 128 + brow) * NODES + jbase))[bseg];
            pc0 = *(const float4*)(c2 + ((size_t)n * C2 + kbase + hcc) * LEN + ib + hig * 4);
        }
#pragma unroll 8
        for (int ii = 0; ii < 8; ++ii) {
            int i = ibase0 + ii;
            float4 bv = *(const float4*)&bt[i * 36 + jq * 4];
            float4 hv = *(const float4*)&ht[i * 20 + kq * 4];
            mx[0][0] = fmaxf(mx[0][0], bv.x * hv.x);
            mx[0][1] = fmaxf(mx[0][1], bv.x * hv.y);
            mx[0][2] = fmaxf(mx[0][2], bv.x * hv.z);
            mx[0][3] = fmaxf(mx[0][3], bv.x * hv.w);
            mx[1][0] = fmaxf(mx[1][0], bv.y * hv.x);
            mx[1][1] = fmaxf(mx[1][1], bv.y * hv.y);
            mx[1][2] = fmaxf(mx[1][2], bv.y * hv.z);
            mx[1][3] = fmaxf(mx[1][3], bv.y * hv.w);
            mx[2][0] = fmaxf(mx[2][0], bv.z * hv.x);
            mx[2][1] = fmaxf(mx[2][1], bv.z * hv.y);
            mx[2][2] = fmaxf(mx[2][2], bv.z * hv.z);
            mx[2][3] = fmaxf(mx[2][3], bv.z * hv.w);
            mx[3][0] = fmaxf(mx[3][0], bv.w * hv.x);
            mx[3][1] = fmaxf(mx[3][1], bv.w * hv.y);
            mx[3][2] = fmaxf(mx[3][2], bv.w * hv.z);
            mx[3][3] = fmaxf(mx[3][3], bv.w * hv.w);
        }
        __syncthreads();
    }

    // combine the two i-halves within the wave, then direct 16-way across waves
#pragma unroll
    for (int a = 0; a < 4; ++a)
#pragma unroll
        for (int c = 0; c < 4; ++c)
            mx[a][c] = fmaxf(mx[a][c], __shfl_xor(mx[a][c], 32));

    float* zpart = smem;            // 16 x 512 = 8192 (bt dead)
    float* zsl   = smem + 9216;     // 512 (ht region)
    if (lane < 32) {
#pragma unroll
        for (int a = 0; a < 4; ++a)
            *(float4*)&zpart[wave * 512 + (jq * 4 + a) * 16 + kq * 4]
                = make_float4(mx[a][0], mx[a][1], mx[a][2], mx[a][3]);
    }
    __syncthreads();
    if (tid < 512) {
        float m = zpart[tid];
#pragma unroll
        for (int p = 1; p < 16; ++p) m = fmaxf(m, zpart[p * 512 + tid]);
        zsl[tid] = m;
    }
    __syncthreads();

    // FC1 slice: 16 waves split 100 features (7,7,7,7,6x12); full-cacheline w1 reads
    {
        int slice = jt * 4 + ks;
        float4 za = *(const float4*)&zsl[lane * 8];
        float4 zb = *(const float4*)&zsl[lane * 8 + 4];
        int jloc = lane >> 1, kq2 = (lane & 1) * 8;
        const float* wb = w1 + (size_t)(jbase + jloc) * 64 + kbase + kq2;
        int f0 = (wave < 4) ? wave * 7 : 28 + (wave - 4) * 6;
        int nf = (wave < 4) ? 7 : 6;
        for (int t = 0; t < nf; ++t) {
            int f = f0 + t;
            const float* wp = wb + (size_t)f * 8192;
            float4 w0 = *(const float4*)wp;
            float4 w1v = *(const float4*)(wp + 4);
            float s = za.x * w0.x + za.y * w0.y + za.z * w0.z + za.w * w0.w
                    + zb.x * w1v.x + zb.y * w1v.y + zb.z * w1v.z + zb.w * w1v.w;
#pragma unroll
            for (int off = 32; off >= 1; off >>= 1) s += __shfl_xor(s, off);
            if (lane == 0)
                atomicExch(&zzp[(size_t)slice * 1600 + n * 100 + f], s);
        }
    }

    // 2-level ticket: drain own exchanges; last-of-16-per-n bumps global; last runs tail
    asm volatile("s_waitcnt vmcnt(0)" ::: "memory");
    __syncthreads();
    if (tid == 0) {
        sflag = 0u;
        if (atomicAdd(&cnt[1 + n], 1u) == 15u)
            if (atomicAdd(&cnt[0], 1u) == 15u) sflag = 1u;
    }
    __syncthreads();
    if (!sflag) return;

    // finisher: combine 16 zzp slices + b1, BN3 over batch, ReLU, FC2 -> out
    float* zzl = smem;          // 1600
    float* sc3 = smem + 1600;   // 100
    float* sh3 = smem + 1700;   // 100

    for (int t = tid; t < BATCH * NF1; t += 1024) {
        float a = 0.f;
#pragma unroll
        for (int sI = 0; sI < 16; ++sI) a += AL(&zzp[(size_t)sI * 1600 + t]);
        zzl[t] = a + b1f[t % NF1];
    }
    __syncthreads();
    if (tid < NF1) {
        float s = 0.f, q = 0.f;
#pragma unroll
        for (int m = 0; m < BATCH; ++m) {
            float v = zzl[m * NF1 + tid];
            s += v; q += v * v;
        }
        float mean = s * (1.f / 16.f);
        float var  = q * (1.f / 16.f) - mean * mean;
        float rs   = rsqrtf(var + EPS);
        float sc   = g3[tid] * rs;
        sc3[tid] = sc;
        sh3[tid] = b3[tid] - mean * sc;
    }
    __syncthreads();
    for (int t = tid; t < BATCH * NF1; t += 1024) {
        int f = t % NF1;
        zzl[t] = fmaxf(0.f, zzl[t] * sc3[f] + sh3[f]);
    }
    __syncthreads();
    {
        int o = tid & 127, grp = tid >> 7;   // 8 groups x 2 batch rows
        float acc0 = b2f[o], acc1 = b2f[o];
        const float* wr = w2 + (size_t)o * NF1;
        for (int f = 0; f < NF1; ++f) {
            float wv = wr[f];
            acc0 += zzl[(grp * 2 + 0) * NF1 + f] * wv;
            acc1 += zzl[(grp * 2 + 1) * NF1 + f] * wv;
        }
        out[(grp * 2 + 0) * NF2 + o] = acc0;
        out[(grp * 2 + 1) * NF2 + o] = acc1;
    }
}

extern "C" void kernel_launch(void* const* d_in, const int* in_sizes, int n_in,
                              void* d_out, int out_size, void* d_ws, size_t ws_size,
                              hipStream_t stream) {
    const float* x    = (const float*)d_in[0];
    const float* bmat = (const float*)d_in[1];
    const float* c1w  = (const float*)d_in[2];
    const float* c1b  = (const float*)d_in[3];
    const float* g1   = (const float*)d_in[4];
    const float* bb1  = (const float*)d_in[5];
    const float* c2w  = (const float*)d_in[6];
    const float* c2b  = (const float*)d_in[7];
    const float* g2   = (const float*)d_in[8];
    const float* bb2  = (const float*)d_in[9];
    const float* w1   = (const float*)d_in[10];
    const float* b1   = (const float*)d_in[11];
    const float* g3   = (const float*)d_in[12];
    const float* b3   = (const float*)d_in[13];
    const float* w2   = (const float*)d_in[14];
    const float* b2   = (const float*)d_in[15];
    float* out = (float*)d_out;
    float* ws  = (float*)d_ws;

    float*    c1  = ws + OFF_C1;
    float*    c2  = ws + OFF_C2;
    float*    s1p = ws + OFF_S1P;
    float*    s2p = ws + OFF_S2P;
    float*    zzp = ws + OFF_ZZP;
    unsigned* cnt = (unsigned*)(ws + OFF_CNT);

    kA<<<256, 512, 0, stream>>>(x, c1w, c1b, c1, s1p);
    kB<<<256, 512, 0, stream>>>(c1, c2w, c2b, g1, bb1, s1p, c2, s2p, cnt);
    kC<<<256, 1024, 0, stream>>>(bmat, c2, g2, bb2, s2p, w1, b1, g3, b3, w2, b2,
                                 zzp, cnt, out);
}

// Round 13
// 135.597 us; speedup vs baseline: 1.1023x; 1.0121x over previous
//
#include <hip/hip_runtime.h>

#define EPS 1e-5f

#define BATCH 16
#define LEN   1024
#define C0    8
#define C1    32
#define C2    64
#define NODES 128
#define NF1   100
#define NF2   128

// workspace layout (float offsets) — round-6 proven. cnt[0..16] zeroed by kB
// (visible to kC via dispatch boundary); zzp fully written before read.
#define OFF_C1   0          // 16*32*1024 = 524288
#define OFF_C2   524288     // 16*64*1024 = 1048576
#define OFF_S1P  1572864    // 256 blocks * 64
#define OFF_S2P  1589248    // 256 blocks * 128
#define OFF_ZZP  1622016    // 16 slices * 16 n * 100 f = 25600
#define OFF_CNT  1647616    // 17 uints: [0]=global, [1+n]=per-n

#define AL(p) __hip_atomic_load((p), __ATOMIC_RELAXED, __HIP_MEMORY_SCOPE_AGENT)

// ---------------- kA: 1024 threads (4 waves/SIMD). conv1 (8->32, K=5, pad 2)
// + bias -> c1, BN1 block partials (2 channels/wave)
__global__ __launch_bounds__(1024)
void kA(const float* __restrict__ x, const float* __restrict__ w,
        const float* __restrict__ bias, float* __restrict__ c1,
        float* __restrict__ s1p) {
    int tid = threadIdx.x, b = blockIdx.x;
    int lane = tid & 63, wave = tid >> 6;          // 16 waves
    int n = b >> 4, lt = b & 15;
    int l = lt * 64 + lane;
    int cg2 = __builtin_amdgcn_readfirstlane(wave * 2);   // 2 channels/wave

    float xr[5][8];
#pragma unroll
    for (int dl = 0; dl < 5; ++dl) {
        int lw = l + dl - 2;
        if (lw >= 0 && lw < LEN) {
            const float4* p = (const float4*)(x + ((size_t)n * LEN + lw) * C0);
            float4 a = p[0], b4 = p[1];
            xr[dl][0] = a.x;  xr[dl][1] = a.y;  xr[dl][2] = a.z;  xr[dl][3] = a.w;
            xr[dl][4] = b4.x; xr[dl][5] = b4.y; xr[dl][6] = b4.z; xr[dl][7] = b4.w;
        } else {
#pragma unroll
            for (int ci = 0; ci < 8; ++ci) xr[dl][ci] = 0.f;
        }
    }
#pragma unroll
    for (int u = 0; u < 2; ++u) {
        int c = cg2 + u;
        float acc = bias[c];
        const float* wc = w + c * 40;
#pragma unroll
        for (int ci = 0; ci < 8; ++ci)
#pragma unroll
            for (int dl = 0; dl < 5; ++dl)
                acc += xr[dl][ci] * wc[ci * 5 + dl];
        c1[((size_t)n * C1 + c) * LEN + l] = acc;

        float s = acc, q = acc * acc;
#pragma unroll
        for (int off = 32; off >= 1; off >>= 1) {
            s += __shfl_xor(s, off);
            q += __shfl_xor(q, off);
        }
        if (lane == 0) {
            s1p[b * 64 + c * 2]     = s;
            s1p[b * 64 + c * 2 + 1] = q;
        }
    }
}

// ---------------- kB: 1024 threads (4 waves/SIMD). BN1 reduce; BN1+ReLU ->
// conv2 (4 ch/wave) -> c2, BN2 partials; zero cnt
__global__ __launch_bounds__(1024)
void kB(const float* __restrict__ c1, const float* __restrict__ w,
        const float* __restrict__ bias,
        const float* __restrict__ g1, const float* __restrict__ bb1,
        const float* __restrict__ s1p,
        float* __restrict__ c2, float* __restrict__ s2p,
        unsigned* __restrict__ cnt) {
    int tid = threadIdx.x, b = blockIdx.x;
    int lane = tid & 63, wave = tid >> 6;          // 16 waves

    if (b == 0 && tid < 17) cnt[tid] = 0u;

    __shared__ float sc1[32], sh1[32];
    __shared__ __align__(16) float a1[32 * 68];
    __shared__ float redw[1024];

    // BN1 reduce: group g = wave (16 groups x 16 producer blocks), value = lane
    {
        float a0=0,a1_=0,a2=0,a3=0,a4=0,a5=0,a6=0,a7=0;
        int b0 = wave * 16;
        for (int i = 0; i < 16; i += 8) {
            a0  += s1p[(size_t)(b0+i  ) * 64 + lane];
            a1_ += s1p[(size_t)(b0+i+1) * 64 + lane];
            a2  += s1p[(size_t)(b0+i+2) * 64 + lane];
            a3  += s1p[(size_t)(b0+i+3) * 64 + lane];
            a4  += s1p[(size_t)(b0+i+4) * 64 + lane];
            a5  += s1p[(size_t)(b0+i+5) * 64 + lane];
            a6  += s1p[(size_t)(b0+i+6) * 64 + lane];
            a7  += s1p[(size_t)(b0+i+7) * 64 + lane];
        }
        redw[wave * 64 + lane] = ((a0+a1_)+(a2+a3)) + ((a4+a5)+(a6+a7));
    }
    __syncthreads();
    if (tid < 64) {
        float s = redw[tid];
#pragma unroll
        for (int g = 1; g < 16; ++g) s += redw[g * 64 + tid];
        redw[tid] = s;
    }
    __syncthreads();
    if (tid < 32) {
        float s = redw[tid * 2], q = redw[tid * 2 + 1];
        float mean = s * (1.f / 16384.f);
        float var  = q * (1.f / 16384.f) - mean * mean;
        float rs   = rsqrtf(var + EPS);
        float sc   = g1[tid] * rs;
        sc1[tid] = sc;
        sh1[tid] = bb1[tid] - mean * sc;
    }
    __syncthreads();

    int n = b >> 4, lt = b & 15;
    int lbase = lt * 64;

    for (int idx = tid; idx < 32 * 68; idx += 1024) {
        int ci = idx / 68, lo = idx - ci * 68;
        int lg = lbase + lo - 2;
        float v = 0.f;
        if (lg >= 0 && lg < LEN) v = c1[((size_t)n * C1 + ci) * LEN + lg];
        a1[idx] = fmaxf(0.f, v * sc1[ci] + sh1[ci]);
    }
    __syncthreads();

    int l = lane;
    int cobase = __builtin_amdgcn_readfirstlane(wave * 4);   // 4 channels/wave

    float acc[4];
#pragma unroll
    for (int u = 0; u < 4; ++u) acc[u] = bias[cobase + u];

    for (int ci = 0; ci < 32; ++ci) {
        float v0 = a1[ci * 68 + l + 0];
        float v1 = a1[ci * 68 + l + 1];
        float v2 = a1[ci * 68 + l + 2];
        float v3 = a1[ci * 68 + l + 3];
        float v4 = a1[ci * 68 + l + 4];
#pragma unroll
        for (int u = 0; u < 4; ++u) {
            const float* wp = w + ((size_t)(cobase + u) * 32 + ci) * 5;
            acc[u] += v0 * wp[0] + v1 * wp[1] + v2 * wp[2] + v3 * wp[3] + v4 * wp[4];
        }
    }

    int lg = lbase + l;
#pragma unroll
    for (int u = 0; u < 4; ++u)
        c2[((size_t)n * C2 + cobase + u) * LEN + lg] = acc[u];

    for (int u = 0; u < 4; ++u) {
        float s = acc[u], q = acc[u] * acc[u];
#pragma unroll
        for (int off = 32; off >= 1; off >>= 1) {
            s += __shfl_xor(s, off);
            q += __shfl_xor(q, off);
        }
        if (lane == 0) {
            int c = cobase + u;
            s2p[b * 128 + c * 2]     = s;
            s2p[b * 128 + c * 2 + 1] = q;
        }
    }
}

// ---------------- kC: 256 blocks x 1024 threads. BN2 reduce; pool (4j x 4k per
// lane, shfl-combined i-halves); FC1 slice -> zzp; 2-level ticket -> BN3+FC2
__global__ __launch_bounds__(1024)
void kC(const float* __restrict__ bmat, const float* __restrict__ c2,
        const float* __restrict__ g2, const float* __restrict__ bb2,
        const float* __restrict__ s2p, const float* __restrict__ w1,
        const float* __restrict__ b1f, const float* __restrict__ g3,
        const float* __restrict__ b3, const float* __restrict__ w2,
        const float* __restrict__ b2f,
        float* __restrict__ zzp, unsigned* __restrict__ cnt,
        float* __restrict__ out) {
    int tid = threadIdx.x, b = blockIdx.x;
    int lane = tid & 63, wave = tid >> 6;          // 16 waves
    int n = b >> 4, jt = (b >> 2) & 3, ks = b & 3;
    int jbase = jt * 32, kbase = ks * 16;

    __shared__ __align__(16) float smem[14368];
    __shared__ unsigned sflag;
    float* bt   = smem;            // 256 x 36 = 9216
    float* ht   = smem + 9216;     // 256 x 20 = 5120 -> 14336
    float* sc2s = smem + 14336;    // 16
    float* sh2s = smem + 14352;    // 16
    float* redw = smem;            // 1024, used before staging (overlaps bt)

    // staging roles
    int brow = tid >> 3, bseg = tid & 7;   // bt: rows brow, brow+128; 8 segs of float4
    int hcc = tid & 15, hig = tid >> 4;    // ht: channel hcc, i-group hig (0..63, 4 i each)

    // issue chunk-0 prefetch FIRST; latency hides under the BN2 reduce
    float4 pb0, pb1, pc0;
    {
        pb0 = ((const float4*)(bmat + ((size_t)n * LEN + brow) * NODES + jbase))[bseg];
        pb1 = ((const float4*)(bmat + ((size_t)n * LEN + 128 + brow) * NODES + jbase))[bseg];
        pc0 = *(const float4*)(c2 + ((size_t)n * C2 + kbase + hcc) * LEN + hig * 4);
    }

    // BN2 reduce: 128 (s,q) values over 256 producer blocks; 8 groups x 32
    {
        int v = tid & 127, grp = tid >> 7;
        float a0=0,a1=0,a2=0,a3=0,a4=0,a5=0,a6=0,a7=0;
        int b0 = grp * 32;
        for (int i = 0; i < 32; i += 8) {
            a0 += s2p[(size_t)(b0+i  ) * 128 + v];
            a1 += s2p[(size_t)(b0+i+1) * 128 + v];
            a2 += s2p[(size_t)(b0+i+2) * 128 + v];
            a3 += s2p[(size_t)(b0+i+3) * 128 + v];
            a4 += s2p[(size_t)(b0+i+4) * 128 + v];
            a5 += s2p[(size_t)(b0+i+5) * 128 + v];
            a6 += s2p[(size_t)(b0+i+6) * 128 + v];
            a7 += s2p[(size_t)(b0+i+7) * 128 + v];
        }
        redw[grp * 128 + v] = ((a0+a1)+(a2+a3)) + ((a4+a5)+(a6+a7));
    }
    __syncthreads();
    if (tid < 128) {
        float s = redw[tid];
#pragma unroll
        for (int g = 1; g < 8; ++g) s += redw[g * 128 + tid];
        redw[tid] = s;
    }
    __syncthreads();
    if (tid < 16) {
        int c = kbase + tid;
        float s = redw[c * 2], q = redw[c * 2 + 1];
        float mean = s * (1.f / 16384.f);
        float var  = q * (1.f / 16384.f) - mean * mean;
        float rs   = rsqrtf(var + EPS);
        float sc   = g2[c] * rs;
        sc2s[tid] = sc;
        sh2s[tid] = bb2[c] - mean * sc;
    }
    __syncthreads();
    float scl = sc2s[hcc], shl = sh2s[hcc];

    // pool roles: lane&31 = combo (jq = combo>>2: 4 j's; kq = combo&3: 4 k's);
    // lane>>5 = i-half. Wave owns 16 rows/chunk; each lane does 8 of them.
    int jq = (lane & 31) >> 2, kq = lane & 3;
    int ibase0 = wave * 16 + (lane >> 5) * 8;
    float mx[4][4];
#pragma unroll
    for (int a = 0; a < 4; ++a)
#pragma unroll
        for (int c = 0; c < 4; ++c) mx[a][c] = 0.f;

    for (int it = 0; it < 4; ++it) {
        // write staged chunk from regs
        *(float4*)&bt[brow * 36 + bseg * 4] = pb0;
        *(float4*)&bt[(brow + 128) * 36 + bseg * 4] = pb1;
        {
            int i0 = hig * 4;
            ht[(i0 + 0) * 20 + hcc] = fmaxf(0.f, pc0.x * scl + shl);
            ht[(i0 + 1) * 20 + hcc] = fmaxf(0.f, pc0.y * scl + shl);
            ht[(i0 + 2) * 20 + hcc] = fmaxf(0.f, pc0.z * scl + shl);
            ht[(i0 + 3) * 20 + hcc] = fmaxf(0.f, pc0.w * scl + shl);
        }
        __syncthreads();
        if (it < 3) {   // prefetch next chunk; hides under pool loop
            int ib = (it + 1) * 256;
            pb0 = ((const float4*)(bmat + ((size_t)n * LEN + ib + brow) * NODES + jbase))[bseg];
            pb1 = ((const float4*)(bmat + ((size_t)n * LEN + ib + 128 + brow) * NODES + jbase))[bseg];
            pc0 = *(const float4*)(c2 + ((size_t)n * C2 + kbase + hcc) * LEN + ib + hig * 4);
        }
#pragma unroll 8
        for (int ii = 0; ii < 8; ++ii) {
            int i = ibase0 + ii;
            float4 bv = *(const float4*)&bt[i * 36 + jq * 4];
            float4 hv = *(const float4*)&ht[i * 20 + kq * 4];
            mx[0][0] = fmaxf(mx[0][0], bv.x * hv.x);
            mx[0][1] = fmaxf(mx[0][1], bv.x * hv.y);
            mx[0][2] = fmaxf(mx[0][2], bv.x * hv.z);
            mx[0][3] = fmaxf(mx[0][3], bv.x * hv.w);
            mx[1][0] = fmaxf(mx[1][0], bv.y * hv.x);
            mx[1][1] = fmaxf(mx[1][1], bv.y * hv.y);
            mx[1][2] = fmaxf(mx[1][2], bv.y * hv.z);
            mx[1][3] = fmaxf(mx[1][3], bv.y * hv.w);
            mx[2][0] = fmaxf(mx[2][0], bv.z * hv.x);
            mx[2][1] = fmaxf(mx[2][1], bv.z * hv.y);
            mx[2][2] = fmaxf(mx[2][2], bv.z * hv.z);
            mx[2][3] = fmaxf(mx[2][3], bv.z * hv.w);
            mx[3][0] = fmaxf(mx[3][0], bv.w * hv.x);
            mx[3][1] = fmaxf(mx[3][1], bv.w * hv.y);
            mx[3][2] = fmaxf(mx[3][2], bv.w * hv.z);
            mx[3][3] = fmaxf(mx[3][3], bv.w * hv.w);
        }
        __syncthreads();
    }

    // combine the two i-halves within the wave, then direct 16-way across waves
#pragma unroll
    for (int a = 0; a < 4; ++a)
#pragma unroll
        for (int c = 0; c < 4; ++c)
            mx[a][c] = fmaxf(mx[a][c], __shfl_xor(mx[a][c], 32));

    float* zpart = smem;            // 16 x 512 = 8192 (bt dead)
    float* zsl   = smem + 9216;     // 512 (ht region)
    if (lane < 32) {
#pragma unroll
        for (int a = 0; a < 4; ++a)
            *(float4*)&zpart[wave * 512 + (jq * 4 + a) * 16 + kq * 4]
                = make_float4(mx[a][0], mx[a][1], mx[a][2], mx[a][3]);
    }
    __syncthreads();
    if (tid < 512) {
        float m = zpart[tid];
#pragma unroll
        for (int p = 1; p < 16; ++p) m = fmaxf(m, zpart[p * 512 + tid]);
        zsl[tid] = m;
    }
    __syncthreads();

    // FC1 slice: 16 waves split 100 features (7,7,7,7,6x12); full-cacheline w1 reads
    {
        int slice = jt * 4 + ks;
        float4 za = *(const float4*)&zsl[lane * 8];
        float4 zb = *(const float4*)&zsl[lane * 8 + 4];
        int jloc = lane >> 1, kq2 = (lane & 1) * 8;
        const float* wb = w1 + (size_t)(jbase + jloc) * 64 + kbase + kq2;
        int f0 = (wave < 4) ? wave * 7 : 28 + (wave - 4) * 6;
        int nf = (wave < 4) ? 7 : 6;
        for (int t = 0; t < nf; ++t) {
            int f = f0 + t;
            const float* wp = wb + (size_t)f * 8192;
            float4 w0 = *(const float4*)wp;
            float4 w1v = *(const float4*)(wp + 4);
            float s = za.x * w0.x + za.y * w0.y + za.z * w0.z + za.w * w0.w
                    + zb.x * w1v.x + zb.y * w1v.y + zb.z * w1v.z + zb.w * w1v.w;
#pragma unroll
            for (int off = 32; off >= 1; off >>= 1) s += __shfl_xor(s, off);
            if (lane == 0)
                atomicExch(&zzp[(size_t)slice * 1600 + n * 100 + f], s);
        }
    }

    // 2-level ticket: drain own exchanges; last-of-16-per-n bumps global; last runs tail
    asm volatile("s_waitcnt vmcnt(0)" ::: "memory");
    __syncthreads();
    if (tid == 0) {
        sflag = 0u;
        if (atomicAdd(&cnt[1 + n], 1u) == 15u)
            if (atomicAdd(&cnt[0], 1u) == 15u) sflag = 1u;
    }
    __syncthreads();
    if (!sflag) return;

    // finisher: combine 16 zzp slices + b1, BN3 over batch, ReLU, FC2 -> out
    float* zzl = smem;          // 1600
    float* sc3 = smem + 1600;   // 100
    float* sh3 = smem + 1700;   // 100

    for (int t = tid; t < BATCH * NF1; t += 1024) {
        float a = 0.f;
#pragma unroll
        for (int sI = 0; sI < 16; ++sI) a += AL(&zzp[(size_t)sI * 1600 + t]);
        zzl[t] = a + b1f[t % NF1];
    }
    __syncthreads();
    if (tid < NF1) {
        float s = 0.f, q = 0.f;
#pragma unroll
        for (int m = 0; m < BATCH; ++m) {
            float v = zzl[m * NF1 + tid];
            s += v; q += v * v;
        }
        float mean = s * (1.f / 16.f);
        float var  = q * (1.f / 16.f) - mean * mean;
        float rs   = rsqrtf(var + EPS);
        float sc   = g3[tid] * rs;
        sc3[tid] = sc;
        sh3[tid] = b3[tid] - mean * sc;
    }
    __syncthreads();
    for (int t = tid; t < BATCH * NF1; t += 1024) {
        int f = t % NF1;
        zzl[t] = fmaxf(0.f, zzl[t] * sc3[f] + sh3[f]);
    }
    __syncthreads();
    {
        int o = tid & 127, grp = tid >> 7;   // 8 groups x 2 batch rows
        float acc0 = b2f[o], acc1 = b2f[o];
        const float* wr = w2 + (size_t)o * NF1;
        for (int f = 0; f < NF1; ++f) {
            float wv = wr[f];
            acc0 += zzl[(grp * 2 + 0) * NF1 + f] * wv;
            acc1 += zzl[(grp * 2 + 1) * NF1 + f] * wv;
        }
        out[(grp * 2 + 0) * NF2 + o] = acc0;
        out[(grp * 2 + 1) * NF2 + o] = acc1;
    }
}

extern "C" void kernel_launch(void* const* d_in, const int* in_sizes, int n_in,
                              void* d_out, int out_size, void* d_ws, size_t ws_size,
                              hipStream_t stream) {
    const float* x    = (const float*)d_in[0];
    const float* bmat = (const float*)d_in[1];
    const float* c1w  = (const float*)d_in[2];
    const float* c1b  = (const float*)d_in[3];
    const float* g1   = (const float*)d_in[4];
    const float* bb1  = (const float*)d_in[5];
    const float* c2w  = (const float*)d_in[6];
    const float* c2b  = (const float*)d_in[7];
    const float* g2   = (const float*)d_in[8];
    const float* bb2  = (const float*)d_in[9];
    const float* w1   = (const float*)d_in[10];
    const float* b1   = (const float*)d_in[11];
    const float* g3   = (const float*)d_in[12];
    const float* b3   = (const float*)d_in[13];
    const float* w2   = (const float*)d_in[14];
    const float* b2   = (const float*)d_in[15];
    float* out = (float*)d_out;
    float* ws  = (float*)d_ws;

    float*    c1  = ws + OFF_C1;
    float*    c2  = ws + OFF_C2;
    float*    s1p = ws + OFF_S1P;
    float*    s2p = ws + OFF_S2P;
    float*    zzp = ws + OFF_ZZP;
    unsigned* cnt = (unsigned*)(ws + OFF_CNT);

    kA<<<256, 1024, 0, stream>>>(x, c1w, c1b, c1, s1p);
    kB<<<256, 1024, 0, stream>>>(c1, c2w, c2b, g1, bb1, s1p, c2, s2p, cnt);
    kC<<<256, 1024, 0, stream>>>(bmat, c2, g2, bb2, s2p, w1, b1, g3, b3, w2, b2,
                                 zzp, cnt, out);
}